// Round 4
// baseline (334.117 us; speedup 1.0000x reference)
//
#include <hip/hip_runtime.h>
#include <hip/hip_bf16.h>

typedef __attribute__((ext_vector_type(8))) short short8;
typedef __attribute__((ext_vector_type(4))) float floatx4;

#define MARGIN 0.3f
static constexpr int N = 8192;   // b*n points
static constexpr int C = 256;    // feature dim

// async 16B global->LDS (dest = wave-uniform base + lane*16)
__device__ __forceinline__ void async16(const void* g, void* l) {
    __builtin_amdgcn_global_load_lds(
        (const __attribute__((address_space(1))) unsigned int*)g,
        (__attribute__((address_space(3))) unsigned int*)l, 16, 0, 0);
}

// ---------------- kernel 0: fp32->bf16 convert + row norms + init --------------
// blocks [0, N/4): one wave per row (4 rows / 256-thr block)
// blocks [N/4, N/4+64): fused mse + dr partial reductions -> scalars[1+b]
__global__ void k_prep_sq(const float* __restrict__ feat, __hip_bfloat16* __restrict__ fb,
                          float* __restrict__ sq, unsigned* __restrict__ posmax,
                          unsigned* __restrict__ negmin,
                          const float* __restrict__ s0, const float* __restrict__ s1,
                          const float* __restrict__ s2, const float* __restrict__ gt,
                          const float* __restrict__ e0, const float* __restrict__ e1,
                          const float* __restrict__ l0, const float* __restrict__ l1,
                          float* __restrict__ scalars, unsigned* __restrict__ done) {
    if (blockIdx.x >= N / 4) {
        const int E = 64 * 1024;
        int bid = blockIdx.x - N / 4;
        if (bid == 0 && threadIdx.x == 0) *done = 0u;
        int tid = bid * 256 + threadIdx.x;
        int nth = 64 * 256;
        float acc = 0.f;
        for (int i = tid; i < E; i += nth) acc += fabsf(e0[i] - l0[i]) * (1.f / E);
        for (int i = tid; i < E; i += nth) acc += fabsf(e1[i] - l1[i]) * (1.f / E);
        if (tid < 192) {
            int k = tid >> 6, i = tid & 63;
            const float* s = (k == 0) ? s0 : ((k == 1) ? s1 : s2);
            float d = s[i] - gt[i];
            acc += d * d * (1.f / 192.f);
        }
#pragma unroll
        for (int off = 32; off; off >>= 1) acc += __shfl_xor(acc, off);
        __shared__ float red[4];
        int lane = threadIdx.x & 63, wv = threadIdx.x >> 6;
        if (lane == 0) red[wv] = acc;
        __syncthreads();
        if (threadIdx.x == 0)
            scalars[1 + bid] = red[0] + red[1] + red[2] + red[3];
        return;
    }
    int row = blockIdx.x * 4 + (threadIdx.x >> 6);
    int lane = threadIdx.x & 63;
    float4 v = ((const float4*)feat)[row * 64 + lane];
    union { __hip_bfloat16 h[4]; ushort4 u; } cv;
    cv.h[0] = __float2bfloat16(v.x); cv.h[1] = __float2bfloat16(v.y);
    cv.h[2] = __float2bfloat16(v.z); cv.h[3] = __float2bfloat16(v.w);
    ((ushort4*)fb)[row * 64 + lane] = cv.u;
    float s = v.x * v.x + v.y * v.y + v.z * v.z + v.w * v.w;
#pragma unroll
    for (int off = 32; off; off >>= 1) s += __shfl_xor(s, off);
    if (lane == 0) {
        sq[row] = s;
        posmax[row] = 0u;
        negmin[row] = 0x7f800000u;   // +inf
    }
}

// ---------------- kernel 1: pairwise mining via bf16 MFMA ----------------------
// FULL matrix (round-1 proven structure), re-tiled for occupancy:
// Grid 1024 = 64 i-tiles x 16 j-chunks (512 cols) -> 4 blocks/CU resident.
// LDS: 2 x 16 KB (32-col B-subtiles, double-buffered) = 32 KB.
// A tile (128 rows x K=256) in registers; row-side mining only; atomics ONLY at
// block end (no per-phase atomic drain). Last block (ticket) finalizes.
__global__ __launch_bounds__(256, 4)
void k_trip(const __hip_bfloat16* __restrict__ fb, const float* __restrict__ sq,
            unsigned* __restrict__ posmax, unsigned* __restrict__ negmin,
            const float* __restrict__ scalars, unsigned* __restrict__ done,
            float* __restrict__ out) {
    __shared__ uint4 Bs[2][1024];   // 2 x (32 cols x 32 granules x 16B) = 32 KB
    __shared__ unsigned sTicket;
    __shared__ float fred[4];

    const int t = threadIdx.x;
    const int w = t >> 6, lane = t & 63;
    const int wi = w >> 1, wj = w & 1;          // 2x2 waves: 64 rows x 16 cols each
    const int quad = lane >> 4, l15 = lane & 15;

    const int ib = (blockIdx.x >> 4) * 128;     // i-tile base row
    const int jc = (blockIdx.x & 15) * 512;     // j-chunk base col

    // ---- A fragments in registers: rows wi*64 + ti*16 + l15, all K=256 ----
    short8 a[4][8];
#pragma unroll
    for (int ti = 0; ti < 4; ++ti) {
        const __hip_bfloat16* ap = fb + (size_t)(ib + wi * 64 + ti * 16 + l15) * C + quad * 8;
#pragma unroll
        for (int k = 0; k < 8; ++k)
            a[ti][k] = *(const short8*)(ap + k * 32);
    }

    // ---- hoisted staging offsets (bf16-element units), 32-col subtile ----
    // slot s (of 1024) holds granule (s&31)^(srow&7) of col srow = s>>5
    int soff[4];
#pragma unroll
    for (int it = 0; it < 4; ++it) {
        int s = it * 256 + t;
        int srow = s >> 5, sg = s & 31;
        soff[it] = srow * C + (sg ^ (srow & 7)) * 8;
    }

    // ---- mining state (statically indexed -> VGPRs) ----
    floatx4 nm[4];                // running min of (sj - 2*dot), [ti][r]
    floatx4 pm;                   // running max over positives, per ti (owner lanes)
#pragma unroll
    for (int q = 0; q < 4; ++q) nm[q] = (floatx4){INFINITY, INFINITY, INFINITY, INFINITY};
    pm = (floatx4){-INFINITY, -INFINITY, -INFINITY, -INFINITY};

    auto STAGE = [&](int p, int cb) {   // stage 32 cols x 256 K into Bs[cb]
        const __hip_bfloat16* src = fb + (size_t)(jc + p * 32) * C;
        uint4* d = &Bs[cb][0] + (t & ~63);
#pragma unroll
        for (int it = 0; it < 4; ++it)
            async16(src + soff[it], d + it * 256);
    };

    auto COMPUTE = [&](int p, int cb) {
        const int jb2 = jc + p * 32;
        const float sj = sq[jb2 + wj * 16 + l15];
        const bool selfblk = (jc + (p >> 2) * 128) == ib;   // col-128-block == row block
        const int cband = (p & 3) * 2 + wj;                 // col band-of-16 in 128-blk

        floatx4 acc[4];
#pragma unroll
        for (int ti = 0; ti < 4; ++ti) acc[ti] = (floatx4){0.f, 0.f, 0.f, 0.f};

        __builtin_amdgcn_s_setprio(1);
#pragma unroll
        for (int k = 0; k < 8; ++k) {
            int col = wj * 16 + l15;
            int g = (k * 4 + quad) ^ (col & 7);
            short8 b = *(const short8*)&Bs[cb][col * 32 + g];
#pragma unroll
            for (int ti = 0; ti < 4; ++ti)
                acc[ti] = __builtin_amdgcn_mfma_f32_16x16x32_bf16(a[ti][k], b, acc[ti], 0, 0, 0);
        }
        __builtin_amdgcn_s_setprio(0);

        // row-side mining epilogue on m = sj - 2*dot
#pragma unroll
        for (int ti = 0; ti < 4; ++ti) {
            bool dtile = (wi * 4 + ti) == cband;            // wave-uniform
#pragma unroll
            for (int r = 0; r < 4; ++r) {
                float v = fmaf(-2.f, acc[ti][r], sj);
                if (dtile) {
                    bool isd = (l15 == quad * 4 + r);       // same label (offset match)
                    nm[ti][r] = fminf(nm[ti][r], isd ? INFINITY : v);
                    if (!selfblk)
                        pm[ti] = fmaxf(pm[ti], isd ? v : -INFINITY);
                } else {
                    nm[ti][r] = fminf(nm[ti][r], v);
                }
            }
        }
    };

    // ---- pipelined main loop: 16 phases, ping-pong LDS ----
    STAGE(0, 0);
    __syncthreads();
#pragma unroll 1
    for (int p = 0; p < 16; ++p) {
        if (p + 1 < 16) STAGE(p + 1, (p + 1) & 1);
        COMPUTE(p, p & 1);
        __syncthreads();
    }

    // ---- end-of-block flush: atomics once ----
#pragma unroll
    for (int ti = 0; ti < 4; ++ti)
#pragma unroll
    for (int r = 0; r < 4; ++r) {
        float v = nm[ti][r];
#pragma unroll
        for (int off = 1; off < 16; off <<= 1) v = fminf(v, __shfl_xor(v, off));
        if (l15 == 0) {
            int row = ib + wi * 64 + ti * 16 + quad * 4 + r;
            float d2 = fmaxf(v + sq[row], 0.f);
            atomicMin(&negmin[row], __float_as_uint(d2));
        }
    }
    if ((l15 >> 2) == quad) {   // owner lanes hold the diag elements
#pragma unroll
        for (int ti = 0; ti < 4; ++ti) {
            int row = ib + wi * 64 + ti * 16 + l15;
            float d2 = fmaxf(pm[ti] + sq[row], 0.f);
            atomicMax(&posmax[row], __float_as_uint(d2));
        }
    }

    // ---- last-block finalize (ticket) ----
    __threadfence();
    __syncthreads();
    if (t == 0) sTicket = atomicAdd(done, 1u);
    __syncthreads();
    if (sTicket == 1023u) {
        __threadfence();
        float acc = 0.f;
        for (int i = t; i < N; i += 256) {
            unsigned pu = __hip_atomic_load(&posmax[i], __ATOMIC_RELAXED, __HIP_MEMORY_SCOPE_AGENT);
            unsigned nu = __hip_atomic_load(&negmin[i], __ATOMIC_RELAXED, __HIP_MEMORY_SCOPE_AGENT);
            float hp = sqrtf(__uint_as_float(pu));
            float hn = sqrtf(__uint_as_float(nu));
            acc += fmaxf(hp - hn + MARGIN, 0.f);
        }
#pragma unroll
        for (int off = 32; off; off >>= 1) acc += __shfl_xor(acc, off);
        if (lane == 0) fred[w] = acc;
        __syncthreads();
        if (t == 0) {
            float tsum = fred[0] + fred[1] + fred[2] + fred[3];
            float ssum = 0.f;
            for (int i = 0; i < 64; ++i)
                ssum += __hip_atomic_load((float*)&scalars[1 + i], __ATOMIC_RELAXED,
                                          __HIP_MEMORY_SCOPE_AGENT);
            out[0] = ssum + tsum * (1.f / N);
        }
    }
}

extern "C" void kernel_launch(void* const* d_in, const int* in_sizes, int n_in,
                              void* d_out, int out_size, void* d_ws, size_t ws_size,
                              hipStream_t stream) {
    const float* feat = (const float*)d_in[0];
    const float* gt   = (const float*)d_in[1];
    const float* s0   = (const float*)d_in[2];
    const float* s1   = (const float*)d_in[3];
    const float* s2   = (const float*)d_in[4];
    const float* e0   = (const float*)d_in[5];
    const float* e1   = (const float*)d_in[6];
    const float* l0   = (const float*)d_in[7];
    const float* l1   = (const float*)d_in[8];
    float* out = (float*)d_out;

    char* ws = (char*)d_ws;
    __hip_bfloat16* fb = (__hip_bfloat16*)ws;                       // 4 MB
    float*    sq      = (float*)(ws + (size_t)N * C * 2);
    unsigned* posmax  = (unsigned*)(ws + (size_t)N * C * 2 + N * 4);
    unsigned* negmin  = (unsigned*)(ws + (size_t)N * C * 2 + N * 8);
    float*    scalars = (float*)(ws + (size_t)N * C * 2 + N * 12);  // 65 floats
    unsigned* done    = (unsigned*)(scalars + 72);

    k_prep_sq<<<N / 4 + 64, 256, 0, stream>>>(feat, fb, sq, posmax, negmin,
                                              s0, s1, s2, gt, e0, e1, l0, l1,
                                              scalars, done);
    k_trip<<<1024, 256, 0, stream>>>(fb, sq, posmax, negmin, scalars, done, out);
}

// Round 5
// 218.223 us; speedup vs baseline: 1.5311x; 1.5311x over previous
//
#include <hip/hip_runtime.h>
#include <hip/hip_bf16.h>

typedef __attribute__((ext_vector_type(8))) short short8;
typedef __attribute__((ext_vector_type(4))) float floatx4;

#define MARGIN 0.3f
static constexpr int N = 8192;   // b*n points
static constexpr int C = 256;    // feature dim

// async 16B global->LDS (dest = wave-uniform base + lane*16)
__device__ __forceinline__ void async16(const void* g, void* l) {
    __builtin_amdgcn_global_load_lds(
        (const __attribute__((address_space(1))) unsigned int*)g,
        (__attribute__((address_space(3))) unsigned int*)l, 16, 0, 0);
}

// ---------------- kernel 0: fp32->bf16 convert + row norms + init --------------
// blocks [0, N/4): one wave per row (4 rows / 256-thr block)
// blocks [N/4, N/4+64): fused mse + dr partial reductions -> scalars[1+b]
__global__ void k_prep_sq(const float* __restrict__ feat, __hip_bfloat16* __restrict__ fb,
                          float* __restrict__ sq, unsigned* __restrict__ posmax,
                          unsigned* __restrict__ negmin,
                          const float* __restrict__ s0, const float* __restrict__ s1,
                          const float* __restrict__ s2, const float* __restrict__ gt,
                          const float* __restrict__ e0, const float* __restrict__ e1,
                          const float* __restrict__ l0, const float* __restrict__ l1,
                          float* __restrict__ scalars, unsigned* __restrict__ done) {
    if (blockIdx.x >= N / 4) {
        const int E = 64 * 1024;
        int bid = blockIdx.x - N / 4;
        if (bid == 0 && threadIdx.x == 0) *done = 0u;
        int tid = bid * 256 + threadIdx.x;
        int nth = 64 * 256;
        float acc = 0.f;
        for (int i = tid; i < E; i += nth) acc += fabsf(e0[i] - l0[i]) * (1.f / E);
        for (int i = tid; i < E; i += nth) acc += fabsf(e1[i] - l1[i]) * (1.f / E);
        if (tid < 192) {
            int k = tid >> 6, i = tid & 63;
            const float* s = (k == 0) ? s0 : ((k == 1) ? s1 : s2);
            float d = s[i] - gt[i];
            acc += d * d * (1.f / 192.f);
        }
#pragma unroll
        for (int off = 32; off; off >>= 1) acc += __shfl_xor(acc, off);
        __shared__ float red[4];
        int lane = threadIdx.x & 63, wv = threadIdx.x >> 6;
        if (lane == 0) red[wv] = acc;
        __syncthreads();
        if (threadIdx.x == 0)
            scalars[1 + bid] = red[0] + red[1] + red[2] + red[3];
        return;
    }
    int row = blockIdx.x * 4 + (threadIdx.x >> 6);
    int lane = threadIdx.x & 63;
    float4 v = ((const float4*)feat)[row * 64 + lane];
    union { __hip_bfloat16 h[4]; ushort4 u; } cv;
    cv.h[0] = __float2bfloat16(v.x); cv.h[1] = __float2bfloat16(v.y);
    cv.h[2] = __float2bfloat16(v.z); cv.h[3] = __float2bfloat16(v.w);
    ((ushort4*)fb)[row * 64 + lane] = cv.u;
    float s = v.x * v.x + v.y * v.y + v.z * v.z + v.w * v.w;
#pragma unroll
    for (int off = 32; off; off >>= 1) s += __shfl_xor(s, off);
    if (lane == 0) {
        sq[row] = s;
        posmax[row] = 0u;
        negmin[row] = 0x7f800000u;   // +inf
    }
}

// ---------------- kernel 1: pairwise mining via bf16 MFMA ----------------------
// FULL matrix, re-tiled for occupancy:
// Grid 1024 = 64 i-tiles x 16 j-chunks (512 cols); LDS 2 x 16 KB (32-col
// B-subtiles, double-buffered) = 32 KB -> LDS allows 4 blocks/CU.
// __launch_bounds__(256, 2): do NOT cap registers below the 128 needed for the
// A fragments (round-4 lesson: min-waves=4 forced arch-VGPR=64 -> A spilled to
// scratch -> 580 MB FETCH). Registers (~128+acc) then set residency at 3-4/CU.
// A tile (128 rows x K=256) in registers; row-side mining only; atomics ONLY at
// block end. Last block (ticket) finalizes.
__global__ __launch_bounds__(256, 2)
void k_trip(const __hip_bfloat16* __restrict__ fb, const float* __restrict__ sq,
            unsigned* __restrict__ posmax, unsigned* __restrict__ negmin,
            const float* __restrict__ scalars, unsigned* __restrict__ done,
            float* __restrict__ out) {
    __shared__ uint4 Bs[2][1024];   // 2 x (32 cols x 32 granules x 16B) = 32 KB
    __shared__ unsigned sTicket;
    __shared__ float fred[4];

    const int t = threadIdx.x;
    const int w = t >> 6, lane = t & 63;
    const int wi = w >> 1, wj = w & 1;          // 2x2 waves: 64 rows x 16 cols each
    const int quad = lane >> 4, l15 = lane & 15;

    const int ib = (blockIdx.x >> 4) * 128;     // i-tile base row
    const int jc = (blockIdx.x & 15) * 512;     // j-chunk base col

    // ---- A fragments in registers: rows wi*64 + ti*16 + l15, all K=256 ----
    short8 a[4][8];
#pragma unroll
    for (int ti = 0; ti < 4; ++ti) {
        const __hip_bfloat16* ap = fb + (size_t)(ib + wi * 64 + ti * 16 + l15) * C + quad * 8;
#pragma unroll
        for (int k = 0; k < 8; ++k)
            a[ti][k] = *(const short8*)(ap + k * 32);
    }

    // ---- hoisted staging offsets (bf16-element units), 32-col subtile ----
    // slot s (of 1024) holds granule (s&31)^(srow&7) of col srow = s>>5
    int soff[4];
#pragma unroll
    for (int it = 0; it < 4; ++it) {
        int s = it * 256 + t;
        int srow = s >> 5, sg = s & 31;
        soff[it] = srow * C + (sg ^ (srow & 7)) * 8;
    }

    // ---- mining state (statically indexed -> VGPRs) ----
    floatx4 nm[4];                // running min of (sj - 2*dot), [ti][r]
    floatx4 pm;                   // running max over positives, per ti (owner lanes)
#pragma unroll
    for (int q = 0; q < 4; ++q) nm[q] = (floatx4){INFINITY, INFINITY, INFINITY, INFINITY};
    pm = (floatx4){-INFINITY, -INFINITY, -INFINITY, -INFINITY};

    auto STAGE = [&](int p, int cb) {   // stage 32 cols x 256 K into Bs[cb]
        const __hip_bfloat16* src = fb + (size_t)(jc + p * 32) * C;
        uint4* d = &Bs[cb][0] + (t & ~63);
#pragma unroll
        for (int it = 0; it < 4; ++it)
            async16(src + soff[it], d + it * 256);
    };

    auto COMPUTE = [&](int p, int cb) {
        const int jb2 = jc + p * 32;
        const float sj = sq[jb2 + wj * 16 + l15];
        const bool selfblk = (jc + (p >> 2) * 128) == ib;   // col-128-block == row block
        const int cband = (p & 3) * 2 + wj;                 // col band-of-16 in 128-blk

        floatx4 acc[4];
#pragma unroll
        for (int ti = 0; ti < 4; ++ti) acc[ti] = (floatx4){0.f, 0.f, 0.f, 0.f};

        __builtin_amdgcn_s_setprio(1);
#pragma unroll
        for (int k = 0; k < 8; ++k) {
            int col = wj * 16 + l15;
            int g = (k * 4 + quad) ^ (col & 7);
            short8 b = *(const short8*)&Bs[cb][col * 32 + g];
#pragma unroll
            for (int ti = 0; ti < 4; ++ti)
                acc[ti] = __builtin_amdgcn_mfma_f32_16x16x32_bf16(a[ti][k], b, acc[ti], 0, 0, 0);
        }
        __builtin_amdgcn_s_setprio(0);

        // row-side mining epilogue on m = sj - 2*dot
#pragma unroll
        for (int ti = 0; ti < 4; ++ti) {
            bool dtile = (wi * 4 + ti) == cband;            // wave-uniform
#pragma unroll
            for (int r = 0; r < 4; ++r) {
                float v = fmaf(-2.f, acc[ti][r], sj);
                if (dtile) {
                    bool isd = (l15 == quad * 4 + r);       // same label (offset match)
                    nm[ti][r] = fminf(nm[ti][r], isd ? INFINITY : v);
                    if (!selfblk)
                        pm[ti] = fmaxf(pm[ti], isd ? v : -INFINITY);
                } else {
                    nm[ti][r] = fminf(nm[ti][r], v);
                }
            }
        }
    };

    // ---- pipelined main loop: 16 phases, ping-pong LDS ----
    STAGE(0, 0);
    __syncthreads();
#pragma unroll 1
    for (int p = 0; p < 16; ++p) {
        if (p + 1 < 16) STAGE(p + 1, (p + 1) & 1);
        COMPUTE(p, p & 1);
        __syncthreads();
    }

    // ---- end-of-block flush: atomics once ----
#pragma unroll
    for (int ti = 0; ti < 4; ++ti)
#pragma unroll
    for (int r = 0; r < 4; ++r) {
        float v = nm[ti][r];
#pragma unroll
        for (int off = 1; off < 16; off <<= 1) v = fminf(v, __shfl_xor(v, off));
        if (l15 == 0) {
            int row = ib + wi * 64 + ti * 16 + quad * 4 + r;
            float d2 = fmaxf(v + sq[row], 0.f);
            atomicMin(&negmin[row], __float_as_uint(d2));
        }
    }
    if ((l15 >> 2) == quad) {   // owner lanes hold the diag elements
#pragma unroll
        for (int ti = 0; ti < 4; ++ti) {
            int row = ib + wi * 64 + ti * 16 + l15;
            float d2 = fmaxf(pm[ti] + sq[row], 0.f);
            atomicMax(&posmax[row], __float_as_uint(d2));
        }
    }

    // ---- last-block finalize (ticket) ----
    __threadfence();
    __syncthreads();
    if (t == 0) sTicket = atomicAdd(done, 1u);
    __syncthreads();
    if (sTicket == 1023u) {
        __threadfence();
        float acc = 0.f;
        for (int i = t; i < N; i += 256) {
            unsigned pu = __hip_atomic_load(&posmax[i], __ATOMIC_RELAXED, __HIP_MEMORY_SCOPE_AGENT);
            unsigned nu = __hip_atomic_load(&negmin[i], __ATOMIC_RELAXED, __HIP_MEMORY_SCOPE_AGENT);
            float hp = sqrtf(__uint_as_float(pu));
            float hn = sqrtf(__uint_as_float(nu));
            acc += fmaxf(hp - hn + MARGIN, 0.f);
        }
#pragma unroll
        for (int off = 32; off; off >>= 1) acc += __shfl_xor(acc, off);
        if (lane == 0) fred[w] = acc;
        __syncthreads();
        if (t == 0) {
            float tsum = fred[0] + fred[1] + fred[2] + fred[3];
            float ssum = 0.f;
            for (int i = 0; i < 64; ++i)
                ssum += __hip_atomic_load((float*)&scalars[1 + i], __ATOMIC_RELAXED,
                                          __HIP_MEMORY_SCOPE_AGENT);
            out[0] = ssum + tsum * (1.f / N);
        }
    }
}

extern "C" void kernel_launch(void* const* d_in, const int* in_sizes, int n_in,
                              void* d_out, int out_size, void* d_ws, size_t ws_size,
                              hipStream_t stream) {
    const float* feat = (const float*)d_in[0];
    const float* gt   = (const float*)d_in[1];
    const float* s0   = (const float*)d_in[2];
    const float* s1   = (const float*)d_in[3];
    const float* s2   = (const float*)d_in[4];
    const float* e0   = (const float*)d_in[5];
    const float* e1   = (const float*)d_in[6];
    const float* l0   = (const float*)d_in[7];
    const float* l1   = (const float*)d_in[8];
    float* out = (float*)d_out;

    char* ws = (char*)d_ws;
    __hip_bfloat16* fb = (__hip_bfloat16*)ws;                       // 4 MB
    float*    sq      = (float*)(ws + (size_t)N * C * 2);
    unsigned* posmax  = (unsigned*)(ws + (size_t)N * C * 2 + N * 4);
    unsigned* negmin  = (unsigned*)(ws + (size_t)N * C * 2 + N * 8);
    float*    scalars = (float*)(ws + (size_t)N * C * 2 + N * 12);  // 65 floats
    unsigned* done    = (unsigned*)(scalars + 72);

    k_prep_sq<<<N / 4 + 64, 256, 0, stream>>>(feat, fb, sq, posmax, negmin,
                                              s0, s1, s2, gt, e0, e1, l0, l1,
                                              scalars, done);
    k_trip<<<1024, 256, 0, stream>>>(fb, sq, posmax, negmin, scalars, done, out);
}

// Round 6
// 166.188 us; speedup vs baseline: 2.0105x; 1.3131x over previous
//
#include <hip/hip_runtime.h>
#include <hip/hip_bf16.h>

typedef __attribute__((ext_vector_type(8))) short short8;
typedef __attribute__((ext_vector_type(4))) float floatx4;

#define MARGIN 0.3f
static constexpr int N = 8192;   // b*n points
static constexpr int C = 256;    // feature dim

// async 16B global->LDS (dest = wave-uniform base + lane*16)
__device__ __forceinline__ void async16(const void* g, void* l) {
    __builtin_amdgcn_global_load_lds(
        (const __attribute__((address_space(1))) unsigned int*)g,
        (__attribute__((address_space(3))) unsigned int*)l, 16, 0, 0);
}

// ---------------- kernel 0: fp32->bf16 convert + row norms + init --------------
// blocks [0, N/4): one wave per row (4 rows / 256-thr block)
// blocks [N/4, N/4+64): fused mse + dr partial reductions -> scalars[1+b]
__global__ void k_prep_sq(const float* __restrict__ feat, __hip_bfloat16* __restrict__ fb,
                          float* __restrict__ sq, unsigned* __restrict__ posmax,
                          unsigned* __restrict__ negmin,
                          const float* __restrict__ s0, const float* __restrict__ s1,
                          const float* __restrict__ s2, const float* __restrict__ gt,
                          const float* __restrict__ e0, const float* __restrict__ e1,
                          const float* __restrict__ l0, const float* __restrict__ l1,
                          float* __restrict__ scalars, unsigned* __restrict__ done) {
    if (blockIdx.x >= N / 4) {
        const int E = 64 * 1024;
        int bid = blockIdx.x - N / 4;
        if (bid == 0 && threadIdx.x == 0) *done = 0u;
        int tid = bid * 256 + threadIdx.x;
        int nth = 64 * 256;
        float acc = 0.f;
        for (int i = tid; i < E; i += nth) acc += fabsf(e0[i] - l0[i]) * (1.f / E);
        for (int i = tid; i < E; i += nth) acc += fabsf(e1[i] - l1[i]) * (1.f / E);
        if (tid < 192) {
            int k = tid >> 6, i = tid & 63;
            const float* s = (k == 0) ? s0 : ((k == 1) ? s1 : s2);
            float d = s[i] - gt[i];
            acc += d * d * (1.f / 192.f);
        }
#pragma unroll
        for (int off = 32; off; off >>= 1) acc += __shfl_xor(acc, off);
        __shared__ float red[4];
        int lane = threadIdx.x & 63, wv = threadIdx.x >> 6;
        if (lane == 0) red[wv] = acc;
        __syncthreads();
        if (threadIdx.x == 0)
            scalars[1 + bid] = red[0] + red[1] + red[2] + red[3];
        return;
    }
    int row = blockIdx.x * 4 + (threadIdx.x >> 6);
    int lane = threadIdx.x & 63;
    float4 v = ((const float4*)feat)[row * 64 + lane];
    union { __hip_bfloat16 h[4]; ushort4 u; } cv;
    cv.h[0] = __float2bfloat16(v.x); cv.h[1] = __float2bfloat16(v.y);
    cv.h[2] = __float2bfloat16(v.z); cv.h[3] = __float2bfloat16(v.w);
    ((ushort4*)fb)[row * 64 + lane] = cv.u;
    float s = v.x * v.x + v.y * v.y + v.z * v.z + v.w * v.w;
#pragma unroll
    for (int off = 32; off; off >>= 1) s += __shfl_xor(s, off);
    if (lane == 0) {
        sq[row] = s;
        posmax[row] = 0u;
        negmin[row] = 0x7f800000u;   // +inf
    }
}

// ---------------- kernel 1: pairwise mining via bf16 MFMA ----------------------
// ROUND-1 PROVEN STRUCTURE (54.5 us), restored verbatim:
// Grid: 64 i-tiles x 8 j-chunks. Block 256 thr = 4 waves (2x2 of 128 rows x 64 cols).
// A tile (128 rows x K=256) in REGISTERS. B streamed in 64-col subtiles through
// two distinct 32 KB LDS buffers (source-XOR-swizzled), prefetch t+1 while
// computing t. Row-side mining only; atomics ONLY at block end.
// Added: last-block (ticket) finalize replaces the k_final launch (~5 us).
// Lesson log: min-waves=4 spills A (R4); 32-col phases double fixed per-phase
// cost (R5); per-phase atomics convoy the drain (R2/R3). Do not repeat.
__global__ __launch_bounds__(256, 2)
void k_trip(const __hip_bfloat16* __restrict__ fb, const float* __restrict__ sq,
            unsigned* __restrict__ posmax, unsigned* __restrict__ negmin,
            const float* __restrict__ scalars, unsigned* __restrict__ done,
            float* __restrict__ out) {
    __shared__ uint4 Bs0[2048];   // 64 cols x 32 granules (16B) = 32 KB
    __shared__ uint4 Bs1[2048];   // ping-pong partner
    __shared__ unsigned sTicket;
    __shared__ float fred[4];

    const int t = threadIdx.x;
    const int ib = (blockIdx.x >> 3) * 128;   // i-tile base row
    const int jc = (blockIdx.x & 7) * 1024;   // j-chunk base
    const int w = t >> 6, lane = t & 63;
    const int wi = w >> 1, wj = w & 1;
    const int quad = lane >> 4, l15 = lane & 15;

    // ---- A fragments in registers: rows wi*64 + ti*16 + l15, all K=256 ----
    short8 a[4][8];
#pragma unroll
    for (int ti = 0; ti < 4; ++ti) {
        const __hip_bfloat16* ap = fb + (size_t)(ib + wi * 64 + ti * 16 + l15) * C + quad * 8;
#pragma unroll
        for (int k = 0; k < 8; ++k)
            a[ti][k] = *(const short8*)(ap + k * 32);
    }

    // ---- hoisted per-thread staging offsets (bf16-element units) ----
    int soff[8];
#pragma unroll
    for (int it = 0; it < 8; ++it) {
        int s = it * 256 + t;
        int srow = s >> 5, sg = s & 31;
        soff[it] = srow * C + (sg ^ (srow & 7)) * 8;
    }

    // mining state: m = (sj - 2*dot); add si at the end.
    float nm[16];                 // per acc-row running min over negatives
    float pm[2];                  // positive max (this wave's diag sub-tiles)
#pragma unroll
    for (int q = 0; q < 16; ++q) nm[q] = INFINITY;
    pm[0] = -INFINITY; pm[1] = -INFINITY;

    auto STAGE = [&](int jb, uint4* dst) {
        const __hip_bfloat16* src = fb + (size_t)jb * C;
        uint4* d = dst + (t & ~63);           // wave-uniform base
#pragma unroll
        for (int it = 0; it < 8; ++it)
            async16(src + soff[it], d + it * 256);
    };

    auto COMPUTE = [&](int jsub, const uint4* __restrict__ Br) {
        floatx4 acc[4][2];
#pragma unroll
        for (int ti = 0; ti < 4; ++ti)
#pragma unroll
            for (int tjj = 0; tjj < 2; ++tjj)
                acc[ti][tjj] = (floatx4){0.f, 0.f, 0.f, 0.f};

        __builtin_amdgcn_s_setprio(1);
#pragma unroll
        for (int k = 0; k < 8; ++k) {
            short8 b[2];
#pragma unroll
            for (int tjj = 0; tjj < 2; ++tjj) {
                int col = wj * 32 + tjj * 16 + l15;
                int g = (k * 4 + quad) ^ (col & 7);
                b[tjj] = *(const short8*)&Br[col * 32 + g];
            }
#pragma unroll
            for (int ti = 0; ti < 4; ++ti)
#pragma unroll
                for (int tjj = 0; tjj < 2; ++tjj)
                    acc[ti][tjj] = __builtin_amdgcn_mfma_f32_16x16x32_bf16(
                        a[ti][k], b[tjj], acc[ti][tjj], 0, 0, 0);
        }
        __builtin_amdgcn_s_setprio(0);

        // mining epilogue on m = sj - 2*dot
        const int jb = jc + jsub * 64;
        const int jb128 = jb & ~127;          // enclosing 128-block base
        const bool par = (wi == (jsub & 1));  // diag band hits this wave-row?
        const bool notself = (jb128 != ib);
#pragma unroll
        for (int tjj = 0; tjj < 2; ++tjj) {
            float sj = sq[jb + wj * 32 + tjj * 16 + l15];
#pragma unroll
            for (int ti = 0; ti < 4; ++ti) {
                bool diag_tile = par && (ti == wj * 2 + tjj);
#pragma unroll
                for (int r = 0; r < 4; ++r) {
                    float v = fmaf(-2.f, acc[ti][tjj][r], sj);
                    if (diag_tile) {
                        bool isd = (l15 == quad * 4 + r);   // same label
                        nm[ti * 4 + r] = fminf(nm[ti * 4 + r], isd ? INFINITY : v);
                        if (notself)
                            pm[tjj] = fmaxf(pm[tjj], isd ? v : -INFINITY);
                    } else {
                        nm[ti * 4 + r] = fminf(nm[ti * 4 + r], v);
                    }
                }
            }
        }
    };

    // ---- 2-phase pipelined main loop: stage t+1 while computing t ----
    STAGE(jc, Bs0);
    __syncthreads();
#pragma unroll 1
    for (int jp = 0; jp < 8; ++jp) {
        STAGE(jc + (jp * 2 + 1) * 64, Bs1);   // prefetch odd subtile
        COMPUTE(jp * 2, Bs0);
        __syncthreads();                       // Bs1 ready; Bs0 reads done
        if (jp < 7)
            STAGE(jc + (jp * 2 + 2) * 64, Bs0); // prefetch next even subtile
        COMPUTE(jp * 2 + 1, Bs1);
        __syncthreads();                       // Bs0 ready; Bs1 reads done
    }

    // ---- final: reduce nm across the 16 lanes of each quad; owner-lane pm ----
#pragma unroll
    for (int q = 0; q < 16; ++q) {
        float v = nm[q];
#pragma unroll
        for (int off = 1; off < 16; off <<= 1) v = fminf(v, __shfl_xor(v, off));
        if (l15 == 0) {
            int row = ib + wi * 64 + (q >> 2) * 16 + quad * 4 + (q & 3);
            float d2 = fmaxf(v + sq[row], 0.f);
            atomicMin(&negmin[row], __float_as_uint(d2));
        }
    }
    if ((l15 >> 2) == quad) {     // this lane owns the tile-diag elems
#pragma unroll
        for (int s = 0; s < 2; ++s) {
            int ti = wj * 2 + s;
            int row = ib + wi * 64 + ti * 16 + l15;
            float d2 = fmaxf(pm[s] + sq[row], 0.f);
            atomicMax(&posmax[row], __float_as_uint(d2));
        }
    }

    // ---- last-block finalize (ticket) -- replaces k_final launch ----
    __threadfence();
    __syncthreads();
    if (t == 0) sTicket = atomicAdd(done, 1u);
    __syncthreads();
    if (sTicket == 511u) {
        __threadfence();
        float acc = 0.f;
        for (int i = t; i < N; i += 256) {
            unsigned pu = __hip_atomic_load(&posmax[i], __ATOMIC_RELAXED, __HIP_MEMORY_SCOPE_AGENT);
            unsigned nu = __hip_atomic_load(&negmin[i], __ATOMIC_RELAXED, __HIP_MEMORY_SCOPE_AGENT);
            float hp = sqrtf(__uint_as_float(pu));
            float hn = sqrtf(__uint_as_float(nu));
            acc += fmaxf(hp - hn + MARGIN, 0.f);
        }
#pragma unroll
        for (int off = 32; off; off >>= 1) acc += __shfl_xor(acc, off);
        if (lane == 0) fred[w] = acc;
        __syncthreads();
        if (t == 0) {
            float tsum = fred[0] + fred[1] + fred[2] + fred[3];
            float ssum = 0.f;
            for (int i = 0; i < 64; ++i)
                ssum += __hip_atomic_load((float*)&scalars[1 + i], __ATOMIC_RELAXED,
                                          __HIP_MEMORY_SCOPE_AGENT);
            out[0] = ssum + tsum * (1.f / N);
        }
    }
}

extern "C" void kernel_launch(void* const* d_in, const int* in_sizes, int n_in,
                              void* d_out, int out_size, void* d_ws, size_t ws_size,
                              hipStream_t stream) {
    const float* feat = (const float*)d_in[0];
    const float* gt   = (const float*)d_in[1];
    const float* s0   = (const float*)d_in[2];
    const float* s1   = (const float*)d_in[3];
    const float* s2   = (const float*)d_in[4];
    const float* e0   = (const float*)d_in[5];
    const float* e1   = (const float*)d_in[6];
    const float* l0   = (const float*)d_in[7];
    const float* l1   = (const float*)d_in[8];
    float* out = (float*)d_out;

    char* ws = (char*)d_ws;
    __hip_bfloat16* fb = (__hip_bfloat16*)ws;                       // 4 MB
    float*    sq      = (float*)(ws + (size_t)N * C * 2);
    unsigned* posmax  = (unsigned*)(ws + (size_t)N * C * 2 + N * 4);
    unsigned* negmin  = (unsigned*)(ws + (size_t)N * C * 2 + N * 8);
    float*    scalars = (float*)(ws + (size_t)N * C * 2 + N * 12);  // 65 floats
    unsigned* done    = (unsigned*)(scalars + 72);

    k_prep_sq<<<N / 4 + 64, 256, 0, stream>>>(feat, fb, sq, posmax, negmin,
                                              s0, s1, s2, gt, e0, e1, l0, l1,
                                              scalars, done);
    k_trip<<<512, 256, 0, stream>>>(fb, sq, posmax, negmin, scalars, done, out);
}

// Round 8
// 131.416 us; speedup vs baseline: 2.5424x; 1.2646x over previous
//
#include <hip/hip_runtime.h>
#include <hip/hip_bf16.h>

typedef __attribute__((ext_vector_type(8))) short short8;
typedef __attribute__((ext_vector_type(4))) float floatx4;

#define MARGIN 0.3f
static constexpr int N = 8192;   // b*n points
static constexpr int C = 256;    // feature dim

// async 16B global->LDS (dest = wave-uniform base + lane*16)
__device__ __forceinline__ void async16(const void* g, void* l) {
    __builtin_amdgcn_global_load_lds(
        (const __attribute__((address_space(1))) unsigned int*)g,
        (__attribute__((address_space(3))) unsigned int*)l, 16, 0, 0);
}

#define MEMFENCE asm volatile("" ::: "memory")
#define BARRIER() do { MEMFENCE; __builtin_amdgcn_s_barrier(); MEMFENCE; } while (0)
#define WAIT_VM(n) asm volatile("s_waitcnt vmcnt(" #n ")" ::: "memory")

// ---------------- kernel 0: fp32->bf16 convert + row norms + init --------------
// blocks [0, N/4): one wave per row (4 rows / 256-thr block)
// blocks [N/4, N/4+64): fused mse + dr partial reductions -> scalars[1+b]
__global__ void k_prep_sq(const float* __restrict__ feat, __hip_bfloat16* __restrict__ fb,
                          float* __restrict__ sq, unsigned* __restrict__ posmax,
                          unsigned* __restrict__ negmin,
                          const float* __restrict__ s0, const float* __restrict__ s1,
                          const float* __restrict__ s2, const float* __restrict__ gt,
                          const float* __restrict__ e0, const float* __restrict__ e1,
                          const float* __restrict__ l0, const float* __restrict__ l1,
                          float* __restrict__ scalars) {
    if (blockIdx.x >= N / 4) {
        const int E = 64 * 1024;
        int bid = blockIdx.x - N / 4;
        int tid = bid * 256 + threadIdx.x;
        int nth = 64 * 256;
        float acc = 0.f;
        for (int i = tid; i < E; i += nth) acc += fabsf(e0[i] - l0[i]) * (1.f / E);
        for (int i = tid; i < E; i += nth) acc += fabsf(e1[i] - l1[i]) * (1.f / E);
        if (tid < 192) {
            int k = tid >> 6, i = tid & 63;
            const float* s = (k == 0) ? s0 : ((k == 1) ? s1 : s2);
            float d = s[i] - gt[i];
            acc += d * d * (1.f / 192.f);
        }
#pragma unroll
        for (int off = 32; off; off >>= 1) acc += __shfl_xor(acc, off);
        __shared__ float red[4];
        int lane = threadIdx.x & 63, wv = threadIdx.x >> 6;
        if (lane == 0) red[wv] = acc;
        __syncthreads();
        if (threadIdx.x == 0)
            scalars[1 + bid] = red[0] + red[1] + red[2] + red[3];
        return;
    }
    int row = blockIdx.x * 4 + (threadIdx.x >> 6);
    int lane = threadIdx.x & 63;
    float4 v = ((const float4*)feat)[row * 64 + lane];
    union { __hip_bfloat16 h[4]; ushort4 u; } cv;
    cv.h[0] = __float2bfloat16(v.x); cv.h[1] = __float2bfloat16(v.y);
    cv.h[2] = __float2bfloat16(v.z); cv.h[3] = __float2bfloat16(v.w);
    ((ushort4*)fb)[row * 64 + lane] = cv.u;
    float s = v.x * v.x + v.y * v.y + v.z * v.z + v.w * v.w;
#pragma unroll
    for (int off = 32; off; off >>= 1) s += __shfl_xor(s, off);
    if (lane == 0) {
        sq[row] = s;
        posmax[row] = 0u;
        negmin[row] = 0x7f800000u;   // +inf
    }
}

// ---------------- kernel 1: pairwise mining via bf16 MFMA ----------------------
// Round-1 geometry (proven 54.5us): grid 64 i-tiles x 8 j-chunks, 4 waves (2x2),
// A (128x256) in registers, B in 64-col subtiles double-buffered in LDS.
// Changes vs round 1:
//  (1) PADDED LDS: col stride 33 uint4 (528 B) instead of 32. Old layout had
//      col*512 = 0 mod 128 -> bank index ignored col -> 8-way conflicts
//      (SQ_LDS_BANK_CONFLICT = 4/read). slot&7 = (l15+4k+quad)&7 now distinct
//      per 8-lane group -> conflict-free. No XOR swizzle needed.
//  (2) counted vmcnt: stage(p+2) issued after the read-done barrier; before
//      compute(p+1) wait only vmcnt(8) -> prefetch stays in flight across
//      barriers, no full drain in the main loop.
// Lesson log: __threadfence() epilogue = per-wave L2 writeback, +40us (R6);
// min-waves=4 spills A (R4); 32-col phases double fixed cost (R5); per-phase
// atomics convoy the drain (R2/R3). Do not repeat.
__global__ __launch_bounds__(256, 2)
void k_trip(const __hip_bfloat16* __restrict__ fb, const float* __restrict__ sq,
            unsigned* __restrict__ posmax, unsigned* __restrict__ negmin) {
    __shared__ uint4 Bs0[2112];   // 64 cols x 33 granules (16B) = 33 KB
    __shared__ uint4 Bs1[2112];   // ping-pong partner

    const int t = threadIdx.x;
    const int ib = (blockIdx.x >> 3) * 128;   // i-tile base row
    const int jc = (blockIdx.x & 7) * 1024;   // j-chunk base
    const int w = t >> 6, lane = t & 63;
    const int wi = w >> 1, wj = w & 1;
    const int quad = lane >> 4, l15 = lane & 15;

    // ---- A fragments in registers: rows wi*64 + ti*16 + l15, all K=256 ----
    short8 a[4][8];
#pragma unroll
    for (int ti = 0; ti < 4; ++ti) {
        const __hip_bfloat16* ap = fb + (size_t)(ib + wi * 64 + ti * 16 + l15) * C + quad * 8;
#pragma unroll
        for (int k = 0; k < 8; ++k)
            a[ti][k] = *(const short8*)(ap + k * 32);
    }

    // ---- staging offsets: LDS slot s holds granule gr=s%33 of col s/33 ----
    // (gr==32 is the pad slot: load a harmless duplicate, never read back)
    int soff[8], soff8;
    {
        auto mk = [](int s) {
            int col = (s * 993) >> 15;          // == s/33 for s < 2112
            int gr = s - col * 33;
            if (gr == 32) gr = 0;               // pad -> duplicate granule 0
            return col * C + gr * 8;            // bf16-element offset
        };
#pragma unroll
        for (int it = 0; it < 8; ++it) soff[it] = mk(it * 256 + t);
        soff8 = mk(2048 + lane);                // extra instr, wave 3 only
    }

    // ---- read column bases (hoisted): addr = colb + 4*k ----
    const int colb0 = (wj * 32 + l15) * 33 + quad;        // tjj = 0
    const int colb1 = (wj * 32 + 16 + l15) * 33 + quad;   // tjj = 1

    // mining state: m = (sj - 2*dot); add si at the end.
    float nm[16];                 // per acc-row running min over negatives
    float pm[2];                  // positive max (this wave's diag sub-tiles)
#pragma unroll
    for (int q = 0; q < 16; ++q) nm[q] = INFINITY;
    pm[0] = -INFINITY; pm[1] = -INFINITY;

    auto STAGE = [&](int jb, uint4* dst) {     // 8 (w3: 9) gload_lds per wave
        const __hip_bfloat16* src = fb + (size_t)jb * C;
        uint4* d = dst + (t & ~63);            // wave-uniform base
#pragma unroll
        for (int it = 0; it < 8; ++it)
            async16(src + soff[it], d + it * 256);
        if (w == 3) async16(src + soff8, dst + 2048);
    };

    auto COMPUTE = [&](int jsub, const uint4* __restrict__ Br) {
        floatx4 acc[4][2];
#pragma unroll
        for (int ti = 0; ti < 4; ++ti)
#pragma unroll
            for (int tjj = 0; tjj < 2; ++tjj)
                acc[ti][tjj] = (floatx4){0.f, 0.f, 0.f, 0.f};

        __builtin_amdgcn_s_setprio(1);
#pragma unroll
        for (int k = 0; k < 8; ++k) {
            short8 b[2];
            b[0] = *(const short8*)&Br[colb0 + 4 * k];
            b[1] = *(const short8*)&Br[colb1 + 4 * k];
#pragma unroll
            for (int ti = 0; ti < 4; ++ti)
#pragma unroll
                for (int tjj = 0; tjj < 2; ++tjj)
                    acc[ti][tjj] = __builtin_amdgcn_mfma_f32_16x16x32_bf16(
                        a[ti][k], b[tjj], acc[ti][tjj], 0, 0, 0);
        }
        __builtin_amdgcn_s_setprio(0);

        // mining epilogue on m = sj - 2*dot
        const int jb = jc + jsub * 64;
        const int jb128 = jb & ~127;          // enclosing 128-block base
        const bool par = (wi == (jsub & 1));  // diag band hits this wave-row?
        const bool notself = (jb128 != ib);
#pragma unroll
        for (int tjj = 0; tjj < 2; ++tjj) {
            float sj = sq[jb + wj * 32 + tjj * 16 + l15];
#pragma unroll
            for (int ti = 0; ti < 4; ++ti) {
                bool diag_tile = par && (ti == wj * 2 + tjj);
#pragma unroll
                for (int r = 0; r < 4; ++r) {
                    float v = fmaf(-2.f, acc[ti][tjj][r], sj);
                    if (diag_tile) {
                        bool isd = (l15 == quad * 4 + r);   // same label
                        nm[ti * 4 + r] = fminf(nm[ti * 4 + r], isd ? INFINITY : v);
                        if (notself)
                            pm[tjj] = fmaxf(pm[tjj], isd ? v : -INFINITY);
                    } else {
                        nm[ti * 4 + r] = fminf(nm[ti * 4 + r], v);
                    }
                }
            }
        }
    };

    // ---- counted-vmcnt pipelined loop: one stage always in flight ----
    STAGE(jc + 0 * 64, Bs0);
    STAGE(jc + 1 * 64, Bs1);
    WAIT_VM(8);                     // A-loads + stage0 done; stage1 may fly
    BARRIER();
#pragma unroll 1
    for (int jp = 0; jp < 8; ++jp) {
        COMPUTE(jp * 2, Bs0);
        BARRIER();                  // all waves done reading Bs0
        if (jp < 7) {
            STAGE(jc + (jp * 2 + 2) * 64, Bs0);
            WAIT_VM(8);             // stage(2jp+1) done; stage(2jp+2) flying
        } else {
            WAIT_VM(0);             // last stage (15) drain
        }
        BARRIER();                  // Bs1 contents visible block-wide
        COMPUTE(jp * 2 + 1, Bs1);
        if (jp == 7) break;
        BARRIER();                  // all waves done reading Bs1
        STAGE(jc + (jp * 2 + 3) * 64, Bs1);
        WAIT_VM(8);                 // stage(2jp+2) done; stage(2jp+3) flying
        BARRIER();                  // Bs0 contents visible block-wide
    }

    // ---- final: reduce nm across the 16 lanes of each quad; owner-lane pm ----
#pragma unroll
    for (int q = 0; q < 16; ++q) {
        float v = nm[q];
#pragma unroll
        for (int off = 1; off < 16; off <<= 1) v = fminf(v, __shfl_xor(v, off));
        if (l15 == 0) {
            int row = ib + wi * 64 + (q >> 2) * 16 + quad * 4 + (q & 3);
            float d2 = fmaxf(v + sq[row], 0.f);
            atomicMin(&negmin[row], __float_as_uint(d2));
        }
    }
    if ((l15 >> 2) == quad) {     // this lane owns the tile-diag elems
#pragma unroll
        for (int s = 0; s < 2; ++s) {
            int ti = wj * 2 + s;
            int row = ib + wi * 64 + ti * 16 + l15;
            float d2 = fmaxf(pm[s] + sq[row], 0.f);
            atomicMax(&posmax[row], __float_as_uint(d2));
        }
    }
}

// ---------------- kernel 2: final combine ---------------------------------------
__global__ void k_final(const unsigned* __restrict__ posmax, const unsigned* __restrict__ negmin,
                        const float* __restrict__ scalars, float* __restrict__ out) {
    float acc = 0.f;
    for (int i = threadIdx.x; i < N; i += 1024) {
        float hp = sqrtf(__uint_as_float(posmax[i]));
        float hn = sqrtf(__uint_as_float(negmin[i]));
        acc += fmaxf(hp - hn + MARGIN, 0.f);
    }
#pragma unroll
    for (int off = 32; off; off >>= 1) acc += __shfl_xor(acc, off);
    __shared__ float red[16];
    if ((threadIdx.x & 63) == 0) red[threadIdx.x >> 6] = acc;
    __syncthreads();
    if (threadIdx.x == 0) {
        float tsum = 0.f;
#pragma unroll
        for (int i = 0; i < 16; ++i) tsum += red[i];
        float ssum = 0.f;
        for (int i = 0; i < 64; ++i) ssum += scalars[1 + i];
        out[0] = ssum + tsum * (1.f / N);
    }
}

extern "C" void kernel_launch(void* const* d_in, const int* in_sizes, int n_in,
                              void* d_out, int out_size, void* d_ws, size_t ws_size,
                              hipStream_t stream) {
    const float* feat = (const float*)d_in[0];
    const float* gt   = (const float*)d_in[1];
    const float* s0   = (const float*)d_in[2];
    const float* s1   = (const float*)d_in[3];
    const float* s2   = (const float*)d_in[4];
    const float* e0   = (const float*)d_in[5];
    const float* e1   = (const float*)d_in[6];
    const float* l0   = (const float*)d_in[7];
    const float* l1   = (const float*)d_in[8];
    float* out = (float*)d_out;

    char* ws = (char*)d_ws;
    __hip_bfloat16* fb = (__hip_bfloat16*)ws;                       // 4 MB
    float*    sq      = (float*)(ws + (size_t)N * C * 2);
    unsigned* posmax  = (unsigned*)(ws + (size_t)N * C * 2 + N * 4);
    unsigned* negmin  = (unsigned*)(ws + (size_t)N * C * 2 + N * 8);
    float*    scalars = (float*)(ws + (size_t)N * C * 2 + N * 12);  // 65 floats

    k_prep_sq<<<N / 4 + 64, 256, 0, stream>>>(feat, fb, sq, posmax, negmin,
                                              s0, s1, s2, gt, e0, e1, l0, l1, scalars);
    k_trip<<<512, 256, 0, stream>>>(fb, sq, posmax, negmin);
    k_final<<<1, 1024, 0, stream>>>(posmax, negmin, scalars, out);
}